// Round 17
// baseline (139.393 us; speedup 1.0000x reference)
//
#include <hip/hip_runtime.h>
#include <stdint.h>

#define HH 56
#define WW 56
#define HW 3136
#define CC 128
#define BB 32
#define NPIX 100352        // B*H*W
#define NTOT 12845056      // B*C*H*W
#define EPSV 1e-5
#define IRS 8192           // image row stride bytes = 64 cols * 128 ch
#define IBS (58 * 8192)    // image batch stride (58 padded rows)
#define W8SZ 147456        // one weight tensor: 9 taps * 8 kc * 128 oc * 16 B

typedef int v4i  __attribute__((ext_vector_type(4)));
typedef int v16i __attribute__((ext_vector_type(16)));

// ---------------- K0: merged prologue.
// blocks [0,1568): pack x signs -> i8 img interior (blocked layout)
// blocks [1568,1808): zero img border cells
// blocks [1808,1817): pack weights (blocked [tap][kc8][oc][16B]) + zero sums
__global__ void k_prologue(const float* __restrict__ x,
                           const float* __restrict__ w1, const float* __restrict__ w2,
                           char* __restrict__ w8L, char* __restrict__ img,
                           unsigned long long* __restrict__ sums1,
                           double* __restrict__ sums2) {
    __shared__ unsigned smP[64][33];
    int tid = threadIdx.x;
    int bid = blockIdx.x;
    if (bid < 1568) {
        // ---- pack_x ----
        int cq = tid >> 6, pl = tid & 63;
        int P0 = bid * 64;
        int pix = P0 + pl;
        int b = pix / HW, r = pix % HW;
        const float* base = x + ((size_t)(b * CC + cq * 32)) * HW + r;
#pragma unroll
        for (int i = 0; i < 8; ++i) {
            unsigned u = 0;
#pragma unroll
            for (int j = 0; j < 4; ++j) {
                float v = base[(size_t)(i * 4 + j) * HW];
                u |= (v > 0.f ? 0x01u : 0xFFu) << (8 * j);
            }
            smP[pl][cq * 8 + i] = u;
        }
        __syncthreads();
#pragma unroll
        for (int ci = tid; ci < 512; ci += 256) {
            int p = ci & 63, kc = ci >> 6;
            int pix2 = P0 + p;
            int b2 = pix2 / HW, r2 = pix2 % HW;
            int h = r2 / WW, w = r2 % WW;
            size_t dst = (size_t)b2 * IBS + (size_t)(h + 1) * IRS + kc * 1024 + (size_t)(w + 1) * 16;
            uint4 v;
            v.x = smP[p][kc * 4 + 0]; v.y = smP[p][kc * 4 + 1];
            v.z = smP[p][kc * 4 + 2]; v.w = smP[p][kc * 4 + 3];
            *reinterpret_cast<uint4*>(img + dst) = v;
        }
    } else if (bid < 1808) {
        // ---- zero borders ----
        int i = (bid - 1568) * 256 + tid;           // 61440 jobs
        if (i >= 61440) return;
        int b = i / 1920, j = i % 1920;
        size_t off;
        if (j < 1024) {
            int row = (j >> 9) ? 57 : 0;
            int cj = j & 511;
            off = (size_t)b * IBS + (size_t)row * IRS + (size_t)cj * 16;
        } else {
            int jj = j - 1024;
            int row = 1 + jj / 16;
            int k = jj % 16;
            int kc = k >> 1;
            int col = (k & 1) ? 57 : 0;
            off = (size_t)b * IBS + (size_t)row * IRS + kc * 1024 + (size_t)col * 16;
        }
        *reinterpret_cast<uint4*>(img + off) = make_uint4(0, 0, 0, 0);
    } else {
        // ---- pack_w + zero accumulators ----
        int gtid = (bid - 1808) * 256 + tid;        // 2304 jobs
        if (gtid < 256) sums1[gtid] = 0ull;
        else if (gtid < 512) sums2[gtid - 256] = 0.0;
        int tensor = gtid / 1152, rem = gtid % 1152;
        int o = rem / 9, tap = rem % 9;
        const float* w = tensor ? w2 : w1;
        char* dstbase = w8L + (size_t)tensor * W8SZ;
#pragma unroll
        for (int kc = 0; kc < 8; ++kc) {
            unsigned u[4];
#pragma unroll
            for (int i = 0; i < 4; ++i) {
                unsigned uu = 0;
#pragma unroll
                for (int j = 0; j < 4; ++j) {
                    int c = kc * 16 + i * 4 + j;
                    float v = w[(size_t)(o * 128 + c) * 9 + tap];
                    uu |= (v > 0.f ? 0x01u : 0xFFu) << (8 * j);
                }
                u[i] = uu;
            }
            uint4 vv; vv.x = u[0]; vv.y = u[1]; vv.z = u[2]; vv.w = u[3];
            *reinterpret_cast<uint4*>(dstbase + ((size_t)(tap * 8 + kc) * 128 + o) * 16) = vv;
        }
    }
}

// MFMA core (K=32), 2 output rows per wave: ROW0 = padded top row of this wave.
// 12 iters x (3 A-loads + 4 B-loads + 6 MFMAs). ch = j*32 + lh*16 + byte.
#define MFMA_CORE2(OC0, ROW0)                                                   \
    const char* wbase = w8 + ((size_t)((OC0) + l31) << 4) + (lh << 11);         \
    const char* ibase = img + (size_t)b * IBS + (size_t)(ROW0) * IRS            \
                        + ((size_t)(w0 + l31) << 4) + (lh << 10);               \
    v16i a0 = {}, a1 = {};                                                      \
    _Pragma("unroll")                                                           \
    for (int dw = 0; dw < 3; ++dw) {                                            \
        _Pragma("unroll")                                                       \
        for (int j = 0; j < 4; ++j) {                                           \
            const char* wt = wbase + dw * 16384 + j * 4096;                     \
            v4i av0 = *reinterpret_cast<const v4i*>(wt);                        \
            v4i av1 = *reinterpret_cast<const v4i*>(wt + 49152);                \
            v4i av2 = *reinterpret_cast<const v4i*>(wt + 98304);                \
            const char* ib = ibase + j * 2048 + dw * 16;                        \
            v4i bv0 = *reinterpret_cast<const v4i*>(ib);                        \
            v4i bv1 = *reinterpret_cast<const v4i*>(ib + 1 * IRS);              \
            v4i bv2 = *reinterpret_cast<const v4i*>(ib + 2 * IRS);              \
            v4i bv3 = *reinterpret_cast<const v4i*>(ib + 3 * IRS);              \
            a0 = __builtin_amdgcn_mfma_i32_32x32x32_i8(av0, bv0, a0, 0, 0, 0);  \
            a0 = __builtin_amdgcn_mfma_i32_32x32x32_i8(av1, bv1, a0, 0, 0, 0);  \
            a0 = __builtin_amdgcn_mfma_i32_32x32x32_i8(av2, bv2, a0, 0, 0, 0);  \
            a1 = __builtin_amdgcn_mfma_i32_32x32x32_i8(av0, bv1, a1, 0, 0, 0);  \
            a1 = __builtin_amdgcn_mfma_i32_32x32x32_i8(av1, bv2, a1, 0, 0, 0);  \
            a1 = __builtin_amdgcn_mfma_i32_32x32x32_i8(av2, bv3, a1, 0, 0, 0);  \
        }                                                                       \
    }

// Block decomp (grid 1792): blk -> b = blk/56; rem = blk%56; quad = rem/4; oct32 = rem%4.
// 4 waves = (half = wid>>1, rp = wid&1); wave = 2 rows x 28 px x 32 oc.

// ---------------- K2: conv1, fragment-native full-line stores, XCD-swizzled.
// launch_bounds(256,7): VGPR cap 73 (vs 44 default) -> deeper load pipelining
// while keeping grid-matched 7 waves/SIMD residency.
__global__ __launch_bounds__(256, 7)
void k_conv1(const char* __restrict__ img, const char* __restrict__ w8,
             short* __restrict__ y1t) {
    int tid = threadIdx.x, wid = tid >> 6, lane = tid & 63;
    int l31 = lane & 31, lh = lane >> 5;
    int blk = (blockIdx.x & 7) * 224 + (blockIdx.x >> 3);   // bijective: 1792 = 8*224
    int b = blk / 56, rem = blk % 56;
    int quad = rem >> 2, oct32 = rem & 3;
    int h0 = quad * 4;
    int half = wid >> 1, rp = wid & 1;
    int w0 = half * 28;
    int oc0 = oct32 * 32;

    MFMA_CORE2(oc0, h0 + rp * 2)

    short* yt = y1t + (size_t)blk * 8192 + (size_t)wid * 2048;
#pragma unroll
    for (int hr = 0; hr < 2; ++hr) {
        v16i acc = hr ? a1 : a0;
#pragma unroll
        for (int r = 0; r < 16; ++r)
            yt[hr * 1024 + r * 64 + lane] = (short)acc[r];  // 128 B full line
    }
}

// ---------------- K3: per-channel exact int sums from fragment-native y1t.
// Block = one conv1 block (16 KB, 128 rows); 128 threads, 1 row each.
__global__ void k_stats_y1(const short* __restrict__ y1t,
                           unsigned long long* __restrict__ isums) {
    __shared__ int ls[32], lss[32];
    int tid = threadIdx.x;
    if (tid < 32) ls[tid] = 0; else if (tid < 64) lss[tid - 32] = 0;
    __syncthreads();
    int blk = blockIdx.x;
    int oct32 = (blk % 56) & 3;
    int r = tid & 15;
    const uint4* q4 = reinterpret_cast<const uint4*>(y1t + (size_t)blk * 8192 + (size_t)tid * 64);
    int sa = 0, ssa = 0, sb = 0, ssb = 0;
#pragma unroll
    for (int i = 0; i < 8; ++i) {
        uint4 v = q4[i];
        int ii = i & 3;
        int s = 0, ss = 0;
#pragma unroll
        for (int w = 0; w < 4; ++w) {
            int px0 = ii * 8 + w * 2;
            unsigned u = (&v.x)[w];
            if (px0 < 28)     { int a = (int)(short)(u & 0xffffu); s += a; ss += a * a; }
            if (px0 + 1 < 28) { int c = (int)(short)(u >> 16);     s += c; ss += c * c; }
        }
        if (i < 4) { sa += s; ssa += ss; } else { sb += s; ssb += ss; }
    }
    int oc_a = (r & 3) + 8 * (r >> 2);              // lh0; lh1 = +4
    atomicAdd(&ls[oc_a], sa);     atomicAdd(&lss[oc_a], ssa);
    atomicAdd(&ls[oc_a + 4], sb); atomicAdd(&lss[oc_a + 4], ssb);
    __syncthreads();
    if (tid < 32) {
        atomicAdd(&isums[oct32 * 32 + tid],       (unsigned long long)(long long)ls[tid]);
        atomicAdd(&isums[128 + oct32 * 32 + tid], (unsigned long long)(long long)lss[tid]);
    }
}

// ---------------- K5: threshold y1t (fragment layout) through BN1, write i8 image.
// Block = one conv1 block: 32 oc x 4 rows x 56 px -> 448 uint4 img cells.
__global__ void k_pack2(const short* __restrict__ y1t,
                        const unsigned long long* __restrict__ sums1,
                        const float* __restrict__ gamma1, const float* __restrict__ beta1,
                        char* __restrict__ img) {
    __shared__ int SG[128], TA[128];
    int tid = threadIdx.x;
    if (tid < 128) {
        long long S = (long long)sums1[tid];
        long long SS = (long long)sums1[128 + tid];
        double N = (double)NPIX;
        double mean = (double)S / N;
        double var = (double)SS / N - mean * mean;
        double rr = 1.0 / sqrt(var + EPSV);
        double s = (double)gamma1[tid] * rr;
        double bb = (double)beta1[tid] - mean * s;
        int sg, A;
        if (s > 0.0) {
            double f = floor(-bb / s);
            sg = 1; A = (int)fmax(-2000.0, fmin(2000.0, f));
        } else if (s < 0.0) {
            double cl = ceil(-bb / s);
            sg = -1; A = -(int)fmax(-2000.0, fmin(2000.0, cl));
        } else {
            sg = 0; A = (bb > 0.0) ? -1 : 0;
        }
        SG[tid] = sg; TA[tid] = A;
    }
    __syncthreads();
    int blk = blockIdx.x;
    int b = blk / 56, rem = blk % 56;
    int quad = rem >> 2, oct32 = rem & 3;
    int h0 = quad * 4;
    const short* yb = y1t + (size_t)blk * 8192;
    for (int job = tid; job < 448; job += 256) {    // (hrow 4) x (kc_l 2) x (px 56)
        int px56 = job % 56;
        int t2 = job / 56;                          // 0..7
        int kc_l = t2 & 1, hrow = t2 >> 1;
        int half = (px56 >= 28), l31 = px56 - half * 28;
        int rp = hrow >> 1, hr = hrow & 1;
        int wid = (half << 1) | rp;
        unsigned u[4];
#pragma unroll
        for (int i = 0; i < 4; ++i) {
            unsigned uu = 0;
#pragma unroll
            for (int j = 0; j < 4; ++j) {
                int ocl = kc_l * 16 + i * 4 + j;    // 0..31 local
                int lhb = (ocl >> 2) & 1;
                int r = (ocl & 3) | ((ocl >> 3) << 2);
                int y = (int)yb[wid * 2048 + hr * 1024 + r * 64 + lhb * 32 + l31];
                int oc = oct32 * 32 + ocl;
                uu |= ((y * SG[oc] > TA[oc]) ? 0x01u : 0xFFu) << (8 * j);
            }
            u[i] = uu;
        }
        int kc_g = oct32 * 2 + kc_l;
        size_t dst = (size_t)b * IBS + (size_t)(h0 + hrow + 1) * IRS + kc_g * 1024
                   + (size_t)(px56 + 1) * 16;
        uint4 vv; vv.x = u[0]; vv.y = u[1]; vv.z = u[2]; vv.w = u[3];
        *reinterpret_cast<uint4*>(img + dst) = vv;
    }
}

// ---------------- K6: conv2 + residual + fused BN2 stats. Residual PREFETCHED
// before the MFMA core; single merged epilogue pass (one barrier), each thread
// owns (ocl = tid>>3, q = tid&7) and its 7 f4-chunks.
__global__ __launch_bounds__(256, 4)
void k_conv2(const char* __restrict__ img, const char* __restrict__ w8,
             const float* __restrict__ resid, float* __restrict__ tout,
             double* __restrict__ dsums) {
    __shared__ float t_lds[32 * 232];               // 29.7 KB
    int tid = threadIdx.x, wid = tid >> 6, lane = tid & 63;
    int l31 = lane & 31, lh = lane >> 5;
    int blk = (blockIdx.x & 7) * 224 + (blockIdx.x >> 3);
    int b = blk / 56, rem = blk % 56;
    int quad = rem >> 2, oct32 = rem & 3;
    int h0 = quad * 4;
    int half = wid >> 1, rp = wid & 1;
    int w0 = half * 28;
    int oc0g = oct32 * 32;

    // Prefetch residual: thread owns ocl = tid>>3, q = tid&7; chunks f4 = i*8+q.
    int ocl_e = tid >> 3, q_e = tid & 7;
    size_t obase = ((size_t)(b * CC + oc0g)) * HW + quad * 224;
    const float* rbase = resid + obase + (size_t)ocl_e * HW + q_e * 4;
    float4 rv[7];
#pragma unroll
    for (int i = 0; i < 7; ++i)
        rv[i] = *reinterpret_cast<const float4*>(rbase + i * 32);

    MFMA_CORE2(oc0g, h0 + rp * 2)

    if (l31 < 28) {
#pragma unroll
        for (int hr = 0; hr < 2; ++hr) {
            v16i acc = hr ? a1 : a0;
#pragma unroll
            for (int r = 0; r < 16; ++r) {
                int ocl = (r & 3) + 8 * (r >> 2) + 4 * lh;
                t_lds[ocl * 232 + (rp * 2 + hr) * 56 + w0 + l31] = (float)acc[r];
            }
        }
    }
    __syncthreads();
    // Merged pass: LDS -> +resid -> global store; Σ/Σ² in registers.
    float* tb = tout + obase + (size_t)ocl_e * HW + q_e * 4;
    double s = 0.0, ss = 0.0;
#pragma unroll
    for (int i = 0; i < 7; ++i) {
        float4 t4 = *reinterpret_cast<float4*>(&t_lds[ocl_e * 232 + (i * 8 + q_e) * 4]);
        t4.x += rv[i].x; t4.y += rv[i].y; t4.z += rv[i].z; t4.w += rv[i].w;
        *reinterpret_cast<float4*>(tb + i * 32) = t4;
        s += (double)t4.x + (double)t4.y + (double)t4.z + (double)t4.w;
        ss += (double)t4.x * t4.x + (double)t4.y * t4.y
            + (double)t4.z * t4.z + (double)t4.w * t4.w;
    }
    s += __shfl_down(s, 1); ss += __shfl_down(ss, 1);
    s += __shfl_down(s, 2); ss += __shfl_down(ss, 2);
    s += __shfl_down(s, 4); ss += __shfl_down(ss, 4);
    if (q_e == 0) {
        atomicAdd(&dsums[oc0g + ocl_e], s);
        atomicAdd(&dsums[128 + oc0g + ocl_e], ss);
    }
}

// ---------------- K7: BN2 + hardtanh, in-place on d_out (float4)
__global__ void k_bn2(float* __restrict__ t, const double* __restrict__ sums2,
                      const float* __restrict__ gamma2, const float* __restrict__ beta2) {
    __shared__ float sA[128], bA[128];
    int tid = threadIdx.x;
    if (tid < 128) {
        double N = (double)NPIX;
        double mean = sums2[tid] / N;
        double var = sums2[128 + tid] / N - mean * mean;
        double rr = 1.0 / sqrt(var + EPSV);
        double s = (double)gamma2[tid] * rr;
        double bb = (double)beta2[tid] - mean * s;
        sA[tid] = (float)s; bA[tid] = (float)bb;
    }
    __syncthreads();
    size_t i4 = ((size_t)blockIdx.x * 256 + tid) * 4;
    int c = (int)((i4 / HW) & 127);
    float4 v = *reinterpret_cast<float4*>(t + i4);
    float s = sA[c], bb = bA[c];
    v.x = fminf(1.f, fmaxf(-1.f, v.x * s + bb));
    v.y = fminf(1.f, fmaxf(-1.f, v.y * s + bb));
    v.z = fminf(1.f, fmaxf(-1.f, v.z * s + bb));
    v.w = fminf(1.f, fmaxf(-1.f, v.w * s + bb));
    *reinterpret_cast<float4*>(t + i4) = v;
}

extern "C" void kernel_launch(void* const* d_in, const int* in_sizes, int n_in,
                              void* d_out, int out_size, void* d_ws, size_t ws_size,
                              hipStream_t stream) {
    const float* x      = (const float*)d_in[0];
    const float* w1     = (const float*)d_in[1];
    const float* w2     = (const float*)d_in[2];
    const float* gamma1 = (const float*)d_in[3];
    const float* beta1  = (const float*)d_in[4];
    const float* gamma2 = (const float*)d_in[5];
    const float* beta2  = (const float*)d_in[6];
    float* out = (float*)d_out;

    char* ws = (char*)d_ws;
    char* w8L = ws;                    ws += 2 * W8SZ;                        // 288 KB
    char* img = ws;                    ws += (size_t)BB * IBS;                // 15.2 MB
    short* y1t = (short*)ws;           ws += (size_t)1792 * 8192 * sizeof(short); // 29.4 MB
    unsigned long long* sums1 = (unsigned long long*)ws; ws += 256 * sizeof(unsigned long long);
    double* sums2 = (double*)ws;       ws += 256 * sizeof(double);

    k_prologue<<<1817, 256, 0, stream>>>(x, w1, w2, w8L, img, sums1, sums2);
    k_conv1<<<1792, 256, 0, stream>>>(img, w8L, y1t);
    k_stats_y1<<<1792, 128, 0, stream>>>(y1t, sums1);
    k_pack2<<<1792, 256, 0, stream>>>(y1t, sums1, gamma1, beta1, img);
    k_conv2<<<1792, 256, 0, stream>>>(img, w8L + W8SZ, x, out, sums2);
    k_bn2<<<12544, 256, 0, stream>>>(out, sums2, gamma2, beta2);
}

// Round 18
// 116.716 us; speedup vs baseline: 1.1943x; 1.1943x over previous
//
#include <hip/hip_runtime.h>
#include <stdint.h>

#define HH 56
#define WW 56
#define HW 3136
#define CC 128
#define BB 32
#define NPIX 100352        // B*H*W
#define NTOT 12845056      // B*C*H*W
#define EPSV 1e-5
#define IRS 8192           // image row stride bytes = 64 cols * 128 ch
#define IBS (58 * 8192)    // image batch stride (58 padded rows)
#define W8SZ 147456        // one weight tensor: 9 taps * 8 kc * 128 oc * 16 B

typedef int v4i  __attribute__((ext_vector_type(4)));
typedef int v16i __attribute__((ext_vector_type(16)));

// ---------------- K0: merged prologue.
// blocks [0,1568): pack x signs -> i8 img interior (blocked layout)
// blocks [1568,1808): zero img border cells
// blocks [1808,1817): pack weights (blocked [tap][kc8][oc][16B]) + zero sums
__global__ void k_prologue(const float* __restrict__ x,
                           const float* __restrict__ w1, const float* __restrict__ w2,
                           char* __restrict__ w8L, char* __restrict__ img,
                           unsigned long long* __restrict__ sums1,
                           double* __restrict__ sums2) {
    __shared__ unsigned smP[64][33];
    int tid = threadIdx.x;
    int bid = blockIdx.x;
    if (bid < 1568) {
        // ---- pack_x ----
        int cq = tid >> 6, pl = tid & 63;
        int P0 = bid * 64;
        int pix = P0 + pl;
        int b = pix / HW, r = pix % HW;
        const float* base = x + ((size_t)(b * CC + cq * 32)) * HW + r;
#pragma unroll
        for (int i = 0; i < 8; ++i) {
            unsigned u = 0;
#pragma unroll
            for (int j = 0; j < 4; ++j) {
                float v = base[(size_t)(i * 4 + j) * HW];
                u |= (v > 0.f ? 0x01u : 0xFFu) << (8 * j);
            }
            smP[pl][cq * 8 + i] = u;
        }
        __syncthreads();
#pragma unroll
        for (int ci = tid; ci < 512; ci += 256) {
            int p = ci & 63, kc = ci >> 6;
            int pix2 = P0 + p;
            int b2 = pix2 / HW, r2 = pix2 % HW;
            int h = r2 / WW, w = r2 % WW;
            size_t dst = (size_t)b2 * IBS + (size_t)(h + 1) * IRS + kc * 1024 + (size_t)(w + 1) * 16;
            uint4 v;
            v.x = smP[p][kc * 4 + 0]; v.y = smP[p][kc * 4 + 1];
            v.z = smP[p][kc * 4 + 2]; v.w = smP[p][kc * 4 + 3];
            *reinterpret_cast<uint4*>(img + dst) = v;
        }
    } else if (bid < 1808) {
        // ---- zero borders ----
        int i = (bid - 1568) * 256 + tid;           // 61440 jobs
        if (i >= 61440) return;
        int b = i / 1920, j = i % 1920;
        size_t off;
        if (j < 1024) {
            int row = (j >> 9) ? 57 : 0;
            int cj = j & 511;
            off = (size_t)b * IBS + (size_t)row * IRS + (size_t)cj * 16;
        } else {
            int jj = j - 1024;
            int row = 1 + jj / 16;
            int k = jj % 16;
            int kc = k >> 1;
            int col = (k & 1) ? 57 : 0;
            off = (size_t)b * IBS + (size_t)row * IRS + kc * 1024 + (size_t)col * 16;
        }
        *reinterpret_cast<uint4*>(img + off) = make_uint4(0, 0, 0, 0);
    } else {
        // ---- pack_w + zero accumulators ----
        int gtid = (bid - 1808) * 256 + tid;        // 2304 jobs
        if (gtid < 256) sums1[gtid] = 0ull;
        else if (gtid < 512) sums2[gtid - 256] = 0.0;
        int tensor = gtid / 1152, rem = gtid % 1152;
        int o = rem / 9, tap = rem % 9;
        const float* w = tensor ? w2 : w1;
        char* dstbase = w8L + (size_t)tensor * W8SZ;
#pragma unroll
        for (int kc = 0; kc < 8; ++kc) {
            unsigned u[4];
#pragma unroll
            for (int i = 0; i < 4; ++i) {
                unsigned uu = 0;
#pragma unroll
                for (int j = 0; j < 4; ++j) {
                    int c = kc * 16 + i * 4 + j;
                    float v = w[(size_t)(o * 128 + c) * 9 + tap];
                    uu |= (v > 0.f ? 0x01u : 0xFFu) << (8 * j);
                }
                u[i] = uu;
            }
            uint4 vv; vv.x = u[0]; vv.y = u[1]; vv.z = u[2]; vv.w = u[3];
            *reinterpret_cast<uint4*>(dstbase + ((size_t)(tap * 8 + kc) * 128 + o) * 16) = vv;
        }
    }
}

// MFMA core (K=32), 2 output rows per wave: ROW0 = padded top row of this wave.
// 12 iters x (3 A-loads + 4 B-loads + 6 MFMAs). ch = j*32 + lh*16 + byte.
#define MFMA_CORE2(OC0, ROW0)                                                   \
    const char* wbase = w8 + ((size_t)((OC0) + l31) << 4) + (lh << 11);         \
    const char* ibase = img + (size_t)b * IBS + (size_t)(ROW0) * IRS            \
                        + ((size_t)(w0 + l31) << 4) + (lh << 10);               \
    v16i a0 = {}, a1 = {};                                                      \
    _Pragma("unroll")                                                           \
    for (int dw = 0; dw < 3; ++dw) {                                            \
        _Pragma("unroll")                                                       \
        for (int j = 0; j < 4; ++j) {                                           \
            const char* wt = wbase + dw * 16384 + j * 4096;                     \
            v4i av0 = *reinterpret_cast<const v4i*>(wt);                        \
            v4i av1 = *reinterpret_cast<const v4i*>(wt + 49152);                \
            v4i av2 = *reinterpret_cast<const v4i*>(wt + 98304);                \
            const char* ib = ibase + j * 2048 + dw * 16;                        \
            v4i bv0 = *reinterpret_cast<const v4i*>(ib);                        \
            v4i bv1 = *reinterpret_cast<const v4i*>(ib + 1 * IRS);              \
            v4i bv2 = *reinterpret_cast<const v4i*>(ib + 2 * IRS);              \
            v4i bv3 = *reinterpret_cast<const v4i*>(ib + 3 * IRS);              \
            a0 = __builtin_amdgcn_mfma_i32_32x32x32_i8(av0, bv0, a0, 0, 0, 0);  \
            a0 = __builtin_amdgcn_mfma_i32_32x32x32_i8(av1, bv1, a0, 0, 0, 0);  \
            a0 = __builtin_amdgcn_mfma_i32_32x32x32_i8(av2, bv2, a0, 0, 0, 0);  \
            a1 = __builtin_amdgcn_mfma_i32_32x32x32_i8(av0, bv1, a1, 0, 0, 0);  \
            a1 = __builtin_amdgcn_mfma_i32_32x32x32_i8(av1, bv2, a1, 0, 0, 0);  \
            a1 = __builtin_amdgcn_mfma_i32_32x32x32_i8(av2, bv3, a1, 0, 0, 0);  \
        }                                                                       \
    }

// Block decomp (grid 1792): blk -> b = blk/56; rem = blk%56; quad = rem/4; oct32 = rem%4.
// 4 waves = (half = wid>>1, rp = wid&1); wave = 2 rows x 28 px x 32 oc.

// ---------------- K2: conv1, fragment-native full-line stores, XCD-swizzled.
// Default launch bounds: compiler picks ~44 VGPR; any tighter cap spills (R17).
__global__ __launch_bounds__(256)
void k_conv1(const char* __restrict__ img, const char* __restrict__ w8,
             short* __restrict__ y1t) {
    int tid = threadIdx.x, wid = tid >> 6, lane = tid & 63;
    int l31 = lane & 31, lh = lane >> 5;
    int blk = (blockIdx.x & 7) * 224 + (blockIdx.x >> 3);   // bijective: 1792 = 8*224
    int b = blk / 56, rem = blk % 56;
    int quad = rem >> 2, oct32 = rem & 3;
    int h0 = quad * 4;
    int half = wid >> 1, rp = wid & 1;
    int w0 = half * 28;
    int oc0 = oct32 * 32;

    MFMA_CORE2(oc0, h0 + rp * 2)

    short* yt = y1t + (size_t)blk * 8192 + (size_t)wid * 2048;
#pragma unroll
    for (int hr = 0; hr < 2; ++hr) {
        v16i acc = hr ? a1 : a0;
#pragma unroll
        for (int r = 0; r < 16; ++r)
            yt[hr * 1024 + r * 64 + lane] = (short)acc[r];  // 128 B full line
    }
}

// ---------------- K3: per-channel exact int sums from fragment-native y1t.
// Block = one conv1 block (16 KB, 128 rows); 128 threads, 1 row each.
__global__ void k_stats_y1(const short* __restrict__ y1t,
                           unsigned long long* __restrict__ isums) {
    __shared__ int ls[32], lss[32];
    int tid = threadIdx.x;
    if (tid < 32) ls[tid] = 0; else if (tid < 64) lss[tid - 32] = 0;
    __syncthreads();
    int blk = blockIdx.x;
    int oct32 = (blk % 56) & 3;
    int r = tid & 15;
    const uint4* q4 = reinterpret_cast<const uint4*>(y1t + (size_t)blk * 8192 + (size_t)tid * 64);
    int sa = 0, ssa = 0, sb = 0, ssb = 0;
#pragma unroll
    for (int i = 0; i < 8; ++i) {
        uint4 v = q4[i];
        int ii = i & 3;
        int s = 0, ss = 0;
#pragma unroll
        for (int w = 0; w < 4; ++w) {
            int px0 = ii * 8 + w * 2;
            unsigned u = (&v.x)[w];
            if (px0 < 28)     { int a = (int)(short)(u & 0xffffu); s += a; ss += a * a; }
            if (px0 + 1 < 28) { int c = (int)(short)(u >> 16);     s += c; ss += c * c; }
        }
        if (i < 4) { sa += s; ssa += ss; } else { sb += s; ssb += ss; }
    }
    int oc_a = (r & 3) + 8 * (r >> 2);              // lh0; lh1 = +4
    atomicAdd(&ls[oc_a], sa);     atomicAdd(&lss[oc_a], ssa);
    atomicAdd(&ls[oc_a + 4], sb); atomicAdd(&lss[oc_a + 4], ssb);
    __syncthreads();
    if (tid < 32) {
        atomicAdd(&isums[oct32 * 32 + tid],       (unsigned long long)(long long)ls[tid]);
        atomicAdd(&isums[128 + oct32 * 32 + tid], (unsigned long long)(long long)lss[tid]);
    }
}

// ---------------- K5: threshold y1t (fragment layout) through BN1, write i8 image.
// Block = one conv1 block: 32 oc x 4 rows x 56 px -> 448 uint4 img cells.
__global__ void k_pack2(const short* __restrict__ y1t,
                        const unsigned long long* __restrict__ sums1,
                        const float* __restrict__ gamma1, const float* __restrict__ beta1,
                        char* __restrict__ img) {
    __shared__ int SG[128], TA[128];
    int tid = threadIdx.x;
    if (tid < 128) {
        long long S = (long long)sums1[tid];
        long long SS = (long long)sums1[128 + tid];
        double N = (double)NPIX;
        double mean = (double)S / N;
        double var = (double)SS / N - mean * mean;
        double rr = 1.0 / sqrt(var + EPSV);
        double s = (double)gamma1[tid] * rr;
        double bb = (double)beta1[tid] - mean * s;
        int sg, A;
        if (s > 0.0) {
            double f = floor(-bb / s);
            sg = 1; A = (int)fmax(-2000.0, fmin(2000.0, f));
        } else if (s < 0.0) {
            double cl = ceil(-bb / s);
            sg = -1; A = -(int)fmax(-2000.0, fmin(2000.0, cl));
        } else {
            sg = 0; A = (bb > 0.0) ? -1 : 0;
        }
        SG[tid] = sg; TA[tid] = A;
    }
    __syncthreads();
    int blk = blockIdx.x;
    int b = blk / 56, rem = blk % 56;
    int quad = rem >> 2, oct32 = rem & 3;
    int h0 = quad * 4;
    const short* yb = y1t + (size_t)blk * 8192;
    for (int job = tid; job < 448; job += 256) {    // (hrow 4) x (kc_l 2) x (px 56)
        int px56 = job % 56;
        int t2 = job / 56;                          // 0..7
        int kc_l = t2 & 1, hrow = t2 >> 1;
        int half = (px56 >= 28), l31 = px56 - half * 28;
        int rp = hrow >> 1, hr = hrow & 1;
        int wid = (half << 1) | rp;
        unsigned u[4];
#pragma unroll
        for (int i = 0; i < 4; ++i) {
            unsigned uu = 0;
#pragma unroll
            for (int j = 0; j < 4; ++j) {
                int ocl = kc_l * 16 + i * 4 + j;    // 0..31 local
                int lhb = (ocl >> 2) & 1;
                int r = (ocl & 3) | ((ocl >> 3) << 2);
                int y = (int)yb[wid * 2048 + hr * 1024 + r * 64 + lhb * 32 + l31];
                int oc = oct32 * 32 + ocl;
                uu |= ((y * SG[oc] > TA[oc]) ? 0x01u : 0xFFu) << (8 * j);
            }
            u[i] = uu;
        }
        int kc_g = oct32 * 2 + kc_l;
        size_t dst = (size_t)b * IBS + (size_t)(h0 + hrow + 1) * IRS + kc_g * 1024
                   + (size_t)(px56 + 1) * 16;
        uint4 vv; vv.x = u[0]; vv.y = u[1]; vv.z = u[2]; vv.w = u[3];
        *reinterpret_cast<uint4*>(img + dst) = vv;
    }
}

// ---------------- K6: conv2 + residual + fused BN2 stats. Residual PREFETCHED
// before the MFMA core; single merged epilogue pass (one barrier), each thread
// owns (ocl = tid>>3, q = tid&7) and its 7 f4-chunks.
__global__ __launch_bounds__(256, 4)
void k_conv2(const char* __restrict__ img, const char* __restrict__ w8,
             const float* __restrict__ resid, float* __restrict__ tout,
             double* __restrict__ dsums) {
    __shared__ float t_lds[32 * 232];               // 29.7 KB
    int tid = threadIdx.x, wid = tid >> 6, lane = tid & 63;
    int l31 = lane & 31, lh = lane >> 5;
    int blk = (blockIdx.x & 7) * 224 + (blockIdx.x >> 3);
    int b = blk / 56, rem = blk % 56;
    int quad = rem >> 2, oct32 = rem & 3;
    int h0 = quad * 4;
    int half = wid >> 1, rp = wid & 1;
    int w0 = half * 28;
    int oc0g = oct32 * 32;

    // Prefetch residual: thread owns ocl = tid>>3, q = tid&7; chunks f4 = i*8+q.
    int ocl_e = tid >> 3, q_e = tid & 7;
    size_t obase = ((size_t)(b * CC + oc0g)) * HW + quad * 224;
    const float* rbase = resid + obase + (size_t)ocl_e * HW + q_e * 4;
    float4 rv[7];
#pragma unroll
    for (int i = 0; i < 7; ++i)
        rv[i] = *reinterpret_cast<const float4*>(rbase + i * 32);

    MFMA_CORE2(oc0g, h0 + rp * 2)

    if (l31 < 28) {
#pragma unroll
        for (int hr = 0; hr < 2; ++hr) {
            v16i acc = hr ? a1 : a0;
#pragma unroll
            for (int r = 0; r < 16; ++r) {
                int ocl = (r & 3) + 8 * (r >> 2) + 4 * lh;
                t_lds[ocl * 232 + (rp * 2 + hr) * 56 + w0 + l31] = (float)acc[r];
            }
        }
    }
    __syncthreads();
    // Merged pass: LDS -> +resid -> global store; Σ/Σ² in registers.
    float* tb = tout + obase + (size_t)ocl_e * HW + q_e * 4;
    double s = 0.0, ss = 0.0;
#pragma unroll
    for (int i = 0; i < 7; ++i) {
        float4 t4 = *reinterpret_cast<float4*>(&t_lds[ocl_e * 232 + (i * 8 + q_e) * 4]);
        t4.x += rv[i].x; t4.y += rv[i].y; t4.z += rv[i].z; t4.w += rv[i].w;
        *reinterpret_cast<float4*>(tb + i * 32) = t4;
        s += (double)t4.x + (double)t4.y + (double)t4.z + (double)t4.w;
        ss += (double)t4.x * t4.x + (double)t4.y * t4.y
            + (double)t4.z * t4.z + (double)t4.w * t4.w;
    }
    s += __shfl_down(s, 1); ss += __shfl_down(ss, 1);
    s += __shfl_down(s, 2); ss += __shfl_down(ss, 2);
    s += __shfl_down(s, 4); ss += __shfl_down(ss, 4);
    if (q_e == 0) {
        atomicAdd(&dsums[oc0g + ocl_e], s);
        atomicAdd(&dsums[128 + oc0g + ocl_e], ss);
    }
}

// ---------------- K7: BN2 + hardtanh, in-place on d_out (float4)
__global__ void k_bn2(float* __restrict__ t, const double* __restrict__ sums2,
                      const float* __restrict__ gamma2, const float* __restrict__ beta2) {
    __shared__ float sA[128], bA[128];
    int tid = threadIdx.x;
    if (tid < 128) {
        double N = (double)NPIX;
        double mean = sums2[tid] / N;
        double var = sums2[128 + tid] / N - mean * mean;
        double rr = 1.0 / sqrt(var + EPSV);
        double s = (double)gamma2[tid] * rr;
        double bb = (double)beta2[tid] - mean * s;
        sA[tid] = (float)s; bA[tid] = (float)bb;
    }
    __syncthreads();
    size_t i4 = ((size_t)blockIdx.x * 256 + tid) * 4;
    int c = (int)((i4 / HW) & 127);
    float4 v = *reinterpret_cast<float4*>(t + i4);
    float s = sA[c], bb = bA[c];
    v.x = fminf(1.f, fmaxf(-1.f, v.x * s + bb));
    v.y = fminf(1.f, fmaxf(-1.f, v.y * s + bb));
    v.z = fminf(1.f, fmaxf(-1.f, v.z * s + bb));
    v.w = fminf(1.f, fmaxf(-1.f, v.w * s + bb));
    *reinterpret_cast<float4*>(t + i4) = v;
}

extern "C" void kernel_launch(void* const* d_in, const int* in_sizes, int n_in,
                              void* d_out, int out_size, void* d_ws, size_t ws_size,
                              hipStream_t stream) {
    const float* x      = (const float*)d_in[0];
    const float* w1     = (const float*)d_in[1];
    const float* w2     = (const float*)d_in[2];
    const float* gamma1 = (const float*)d_in[3];
    const float* beta1  = (const float*)d_in[4];
    const float* gamma2 = (const float*)d_in[5];
    const float* beta2  = (const float*)d_in[6];
    float* out = (float*)d_out;

    char* ws = (char*)d_ws;
    char* w8L = ws;                    ws += 2 * W8SZ;                        // 288 KB
    char* img = ws;                    ws += (size_t)BB * IBS;                // 15.2 MB
    short* y1t = (short*)ws;           ws += (size_t)1792 * 8192 * sizeof(short); // 29.4 MB
    unsigned long long* sums1 = (unsigned long long*)ws; ws += 256 * sizeof(unsigned long long);
    double* sums2 = (double*)ws;       ws += 256 * sizeof(double);

    k_prologue<<<1817, 256, 0, stream>>>(x, w1, w2, w8L, img, sums1, sums2);
    k_conv1<<<1792, 256, 0, stream>>>(img, w8L, y1t);
    k_stats_y1<<<1792, 128, 0, stream>>>(y1t, sums1);
    k_pack2<<<1792, 256, 0, stream>>>(y1t, sums1, gamma1, beta1, img);
    k_conv2<<<1792, 256, 0, stream>>>(img, w8L + W8SZ, x, out, sums2);
    k_bn2<<<12544, 256, 0, stream>>>(out, sums2, gamma2, beta2);
}